// Round 4
// baseline (258.719 us; speedup 1.0000x reference)
//
#include <hip/hip_runtime.h>
#include <cstdint>
#include <cstddef>

typedef __attribute__((ext_vector_type(8))) _Float16 f16x8;
typedef __attribute__((ext_vector_type(16))) float f32x16;

#define LO_SCALE 2048.0f
#define LO_INV   (1.0f / 2048.0f)

union H8 { f16x8 v; _Float16 h[8]; };

// ---------------------------------------------------------------------------
// Fused kernel A+C.
// Blocks [0,768): ka_weff_blob — Weff + direct MFMA-A-fragment blob write.
//   Block = (l, nf, ks, h) tile: thread owns row o=nf*32+(tid>>3),
//   i=ks*16+h*8+(tid&7); reads its HWh row sequentially (float4, 1-chunk
//   prefetch), accumulates acc[32] (one per frame) vs latents staged in LDS
//   transposed [k][f] (broadcast reads, conflict-free). Epilogue adds Wh,
//   splits hi/lo fp16, writes blob: per (tl): [nf(8)][ks(16)][part(2)][512].
// Blocks [768,1024): kc_small — layer-0 blob + effective biases.
//   w0blob per t: [nf(8)][part(2)][512 halves]
//   beff: [t][k(4)][256] fp32, k=0: b0+hb0, k>=1: bh[k-1]+hb[k]
// ---------------------------------------------------------------------------
__global__ __launch_bounds__(256) void kab(
    const float* __restrict__ latents, const float* __restrict__ W0,
    const float* __restrict__ b0, const float* __restrict__ bh,
    const float* __restrict__ HW0, const float* __restrict__ HB,
    const float* __restrict__ Wh, const float* __restrict__ HWh,
    _Float16* __restrict__ w0blob, float* __restrict__ beff,
    _Float16* __restrict__ whblob) {
  __shared__ float lat_t[8192];  // [k][f] : 256 x 32
  int tid = threadIdx.x, bid = blockIdx.x;

  if (bid >= 768) {
    // ---------------- kc_small ----------------
    int id = (bid - 768) * 256 + tid;
    if (id < 32768) {
      int t = id >> 10, rem = id & 1023;
      int r2 = rem & 127, part = r2 >> 6, lane = r2 & 63;
      int nf = rem >> 7;
      int o = nf * 32 + (lane & 31), kc = lane >> 5;
      const float* lat = latents + t * 256;
      H8 outv;
#pragma unroll
      for (int j = 0; j < 8; ++j) outv.h[j] = (_Float16)0.0f;
#pragma unroll
      for (int j = 0; j < 8; ++j) {
        int i = kc * 8 + j;
        if (i < 3) {
          const float* row = HW0 + (o * 3 + i) * 256;
          float s = W0[o * 3 + i];
          for (int k = 0; k < 256; k += 4)
            s += row[k] * lat[k] + row[k + 1] * lat[k + 1] +
                 row[k + 2] * lat[k + 2] + row[k + 3] * lat[k + 3];
          _Float16 hi = (_Float16)s;
          outv.h[j] = part ? (_Float16)((s - (float)hi) * LO_SCALE) : hi;
        }
      }
      *(f16x8*)(w0blob + (size_t)id * 8) = outv.v;
    } else {
      int v = id - 32768;
      int t = v >> 10, k = (v >> 8) & 3, hm = v & 255;
      float base = (k == 0) ? b0[hm] : bh[(k - 1) * 256 + hm];
      const float* lat = latents + t * 256;
      const float* row = HB + (size_t)(k * 256 + hm) * 256;
      float s = base;
      for (int kk = 0; kk < 256; kk += 4)
        s += row[kk] * lat[kk] + row[kk + 1] * lat[kk + 1] +
             row[kk + 2] * lat[kk + 2] + row[kk + 3] * lat[kk + 3];
      beff[v] = s;
    }
    return;
  }

  // ---------------- ka_weff_blob ----------------
  int h = bid & 1, ks = (bid >> 1) & 15, nf = (bid >> 5) & 7, l = bid >> 8;

  {
    int f = tid >> 3, kb = (tid & 7) * 32;
#pragma unroll
    for (int m = 0; m < 32; m += 4) {
      float4 v = *(const float4*)(latents + f * 256 + kb + m);
      lat_t[(kb + m + 0) * 32 + f] = v.x;
      lat_t[(kb + m + 1) * 32 + f] = v.y;
      lat_t[(kb + m + 2) * 32 + f] = v.z;
      lat_t[(kb + m + 3) * 32 + f] = v.w;
    }
  }
  __syncthreads();

  int oo = tid >> 3, jj = tid & 7;
  int o = nf * 32 + oo;
  int i = ks * 16 + h * 8 + jj;
  int r = o * 256 + i;
  const float* rowp = HWh + ((size_t)l * 65536 + (size_t)r) * 256;

  float acc[32];
#pragma unroll
  for (int f = 0; f < 32; ++f) acc[f] = 0.f;

  float curf[16], nxtf[16];
#pragma unroll
  for (int q = 0; q < 4; ++q)
    *(float4*)(curf + q * 4) = *(const float4*)(rowp + q * 4);

  for (int kc = 0; kc < 16; ++kc) {
    if (kc < 15) {
#pragma unroll
      for (int q = 0; q < 4; ++q)
        *(float4*)(nxtf + q * 4) = *(const float4*)(rowp + (kc + 1) * 16 + q * 4);
    }
    const float* lp = lat_t + kc * 512;
#pragma unroll
    for (int m = 0; m < 16; ++m) {
      float hw = curf[m];
#pragma unroll
      for (int fq = 0; fq < 8; ++fq) {
        float4 lv = *(const float4*)(lp + m * 32 + fq * 4);
        acc[fq * 4 + 0] += hw * lv.x;
        acc[fq * 4 + 1] += hw * lv.y;
        acc[fq * 4 + 2] += hw * lv.z;
        acc[fq * 4 + 3] += hw * lv.w;
      }
    }
#pragma unroll
    for (int q = 0; q < 16; ++q) curf[q] = nxtf[q];
  }

  float whv = Wh[l * 65536 + r];
  size_t cbase = (size_t)(nf * 16 + ks) * 1024 + (size_t)h * 256 + (size_t)tid;
#pragma unroll
  for (int t = 0; t < 32; ++t) {
    float w = acc[t] + whv;
    _Float16 hi = (_Float16)w;
    _Float16 lo = (_Float16)((w - (float)hi) * LO_SCALE);
    size_t b = (size_t)(t * 3 + l) * 131072 + cbase;
    whblob[b] = hi;
    whblob[b + 512] = lo;
  }
}

// ---------------------------------------------------------------------------
// Kernel B: fused SIREN. Block = one frame x 32 pixels, 8 waves (512 thr),
// each wave owns a 32-wide o-slice (nf = wave id); single 32x32 output tile.
// Transposed GEMM: D[o][px] = sum_k Weff[o][k]*x[px][k] via
// mfma_f32_32x32x16_f16, split-fp16 (hh -> accA; hl + lh (lo pre-scaled 2048)
// -> accB; result = accA+accB/2048). x in LDS as hi/lo fp16 arrays.
// LDS ~39KB, launch_bounds(512,6) -> 3 blocks/CU (24 waves/CU) for
// phase-decorrelated MFMA/VALU overlap.
// ---------------------------------------------------------------------------
__global__ __launch_bounds__(512, 6) void kb_siren(
    const float* __restrict__ coords, const _Float16* __restrict__ whblob,
    const _Float16* __restrict__ w0blob, const float* __restrict__ beff,
    const float* __restrict__ Wf, const float* __restrict__ bf,
    float* __restrict__ out) {
  __shared__ _Float16 xs_hi[32 * 264];
  __shared__ _Float16 xs_lo[32 * 264];
  __shared__ float wf_s[768];
  __shared__ float red[768];  // [wv(8)][px(32)][3]
  int tid = threadIdx.x;
  int bid0 = blockIdx.x;
  int bid = (bid0 & 7) * 512 + (bid0 >> 3);  // XCD swizzle: 4 frames per XCD
  int t = bid >> 7, tile = bid & 127;
  int wv = tid >> 6, lane = tid & 63, col = lane & 31, h = lane >> 5;

  if (tid < 192) *(float4*)(wf_s + tid * 4) = *(const float4*)(Wf + tid * 4);
  if (tid < 32) {
    const float* cp = coords + (size_t)(t * 4096 + tile * 32 + tid) * 3;
    float c0 = cp[0], c1 = cp[1], c2 = cp[2];
    H8 hv, lv, z;
#pragma unroll
    for (int j = 0; j < 8; ++j) { hv.h[j] = (_Float16)0.f; lv.h[j] = (_Float16)0.f; z.h[j] = (_Float16)0.f; }
    _Float16 h0 = (_Float16)c0, h1 = (_Float16)c1, h2 = (_Float16)c2;
    hv.h[0] = h0; hv.h[1] = h1; hv.h[2] = h2;
    lv.h[0] = (_Float16)((c0 - (float)h0) * LO_SCALE);
    lv.h[1] = (_Float16)((c1 - (float)h1) * LO_SCALE);
    lv.h[2] = (_Float16)((c2 - (float)h2) * LO_SCALE);
    *(f16x8*)(xs_hi + tid * 264) = hv.v;
    *(f16x8*)(xs_lo + tid * 264) = lv.v;
    *(f16x8*)(xs_hi + tid * 264 + 8) = z.v;
    *(f16x8*)(xs_lo + tid * 264 + 8) = z.v;
  }
  __syncthreads();

  f32x16 accA, accB;

  auto init_bias = [&](int bk) {
    const float* bp = beff + ((t * 4 + bk) << 8) + wv * 32 + h * 4;
#pragma unroll
    for (int rq = 0; rq < 4; ++rq) {
      float4 bvv = *(const float4*)(bp + rq * 8);
      float ba[4];
      *(float4*)ba = bvv;
#pragma unroll
      for (int q = 0; q < 4; ++q) {
        accA[rq * 4 + q] = ba[q];
        accB[rq * 4 + q] = 0.f;
      }
    }
  };

  auto load_a = [&](const _Float16* blobL, int NS, int ks, f16x8 (&a)[2]) {
    const _Float16* p = blobL + (size_t)((wv * NS + ks) * 2) * 512 + lane * 8;
    a[0] = *(const f16x8*)p;
    a[1] = *(const f16x8*)(p + 512);
  };

  auto load_b = [&](int ks, f16x8 (&b)[2]) {
    int off = col * 264 + ks * 16 + h * 8;
    b[0] = *(const f16x8*)(xs_hi + off);
    b[1] = *(const f16x8*)(xs_lo + off);
  };

  auto mfma3 = [&](f16x8 (&a)[2], f16x8 (&b)[2]) {
    accA = __builtin_amdgcn_mfma_f32_32x32x16_f16(a[0], b[0], accA, 0, 0, 0);
    accB = __builtin_amdgcn_mfma_f32_32x32x16_f16(a[0], b[1], accB, 0, 0, 0);
    accB = __builtin_amdgcn_mfma_f32_32x32x16_f16(a[1], b[0], accB, 0, 0, 0);
  };

  // sine + split + in-register transpose (C rows=o -> B-frag k-contig) + store
  auto epilogue = [&]() {
#pragma unroll
    for (int r = 0; r < 16; ++r)
      accA[r] = __sinf(30.0f * (accA[r] + accB[r] * LO_INV));
    __syncthreads();  // all waves done reading xs for this layer
#pragma unroll
    for (int g = 0; g < 2; ++g) {
      float seq[8];
#pragma unroll
      for (int q = 0; q < 4; ++q) {
        float oa = accA[8 * g + q];       // row g*16 + q + 4h
        float ob = accA[8 * g + 4 + q];   // row g*16 + 8 + q + 4h
        float send = h ? oa : ob;
        float recv = __shfl_xor(send, 32, 64);
        seq[q]     = h ? recv : oa;
        seq[4 + q] = h ? ob : recv;
      }
      H8 hv, lv;
#pragma unroll
      for (int j = 0; j < 8; ++j) {
        _Float16 hi = (_Float16)seq[j];
        hv.h[j] = hi;
        lv.h[j] = (_Float16)((seq[j] - (float)hi) * LO_SCALE);
      }
      int off = col * 264 + wv * 32 + g * 16 + h * 8;
      *(f16x8*)(xs_hi + off) = hv.v;
      *(f16x8*)(xs_lo + off) = lv.v;
    }
    __syncthreads();
  };

  // ---- layer 0 (k=16, mostly zero-padded; coords staged in xs[.., 0..15])
  init_bias(0);
  {
    f16x8 a[2], b[2];
    load_a(w0blob + (size_t)t * 8192, 1, 0, a);
    load_b(0, b);
    mfma3(a, b);
  }
  epilogue();

  // ---- hidden layers
  for (int li = 0; li < 3; ++li) {
    init_bias(li + 1);
    const _Float16* bl = whblob + (size_t)(t * 3 + li) * 131072;
#pragma unroll
    for (int ks = 0; ks < 16; ++ks) {
      f16x8 a[2], b[2];
      load_a(bl, 16, ks, a);
      load_b(ks, b);
      mfma3(a, b);
    }
    epilogue();
  }

  // ---- final linear (3 outputs), VALU from LDS; 16 k-groups of 16
  {
    float pc0 = 0.f, pc1 = 0.f, pc2 = 0.f;
    int px = tid & 31, kq = tid >> 5;  // kq = wv*2 + h
#pragma unroll
    for (int cc = 0; cc < 2; ++cc) {
      int k0 = kq * 16 + cc * 8;
      H8 hv, lv;
      hv.v = *(const f16x8*)(xs_hi + px * 264 + k0);
      lv.v = *(const f16x8*)(xs_lo + px * 264 + k0);
#pragma unroll
      for (int j = 0; j < 8; ++j) {
        float xv = (float)hv.h[j] + (float)lv.h[j] * LO_INV;
        pc0 += xv * wf_s[k0 + j];
        pc1 += xv * wf_s[256 + k0 + j];
        pc2 += xv * wf_s[512 + k0 + j];
      }
    }
    // combine the two k-halves held by lanes l and l+32 (same px)
    pc0 += __shfl_xor(pc0, 32, 64);
    pc1 += __shfl_xor(pc1, 32, 64);
    pc2 += __shfl_xor(pc2, 32, 64);
    if (h == 0) {
      red[wv * 96 + px * 3 + 0] = pc0;
      red[wv * 96 + px * 3 + 1] = pc1;
      red[wv * 96 + px * 3 + 2] = pc2;
    }
    __syncthreads();
    if (tid < 96) {
      int p2 = tid / 3, c = tid - p2 * 3;
      float s = bf[c];
#pragma unroll
      for (int q = 0; q < 8; ++q) s += red[q * 96 + p2 * 3 + c];
      out[(size_t)(t * 4096 + tile * 32 + p2) * 3 + c] = s;
    }
  }
}

// ---------------------------------------------------------------------------
extern "C" void kernel_launch(void* const* d_in, const int* in_sizes, int n_in,
                              void* d_out, int out_size, void* d_ws, size_t ws_size,
                              hipStream_t stream) {
  const float* coords  = (const float*)d_in[0];
  const float* latents = (const float*)d_in[1];
  const float* W0      = (const float*)d_in[2];
  const float* b0      = (const float*)d_in[3];
  const float* Wh      = (const float*)d_in[4];
  const float* bh      = (const float*)d_in[5];
  const float* Wf      = (const float*)d_in[6];
  const float* bf      = (const float*)d_in[7];
  const float* HW0     = (const float*)d_in[8];
  const float* HWh     = (const float*)d_in[9];
  const float* HB      = (const float*)d_in[10];
  float* outp = (float*)d_out;

  char* w = (char*)d_ws;
  _Float16* whblob = (_Float16*)w;                   // 12,582,912 halves
  _Float16* w0blob = (_Float16*)(w + 25165824);      // 262,144 halves
  float*    beff   = (float*)(w + 25690112);         // 32,768 floats

  kab<<<1024, 256, 0, stream>>>(latents, W0, b0, bh, HW0, HB, Wh, HWh,
                                w0blob, beff, whblob);
  kb_siren<<<4096, 512, 0, stream>>>(coords, whblob, w0blob, beff, Wf, bf, outp);
}

// Round 5
// 227.137 us; speedup vs baseline: 1.1390x; 1.1390x over previous
//
#include <hip/hip_runtime.h>
#include <cstdint>
#include <cstddef>

typedef __attribute__((ext_vector_type(8))) _Float16 f16x8;
typedef __attribute__((ext_vector_type(16))) float f32x16;

#define LO_SCALE 2048.0f
#define LO_INV   (1.0f / 2048.0f)

union H8 { f16x8 v; _Float16 h[8]; };

// ---------------------------------------------------------------------------
// Fused kernel A+C.
// Blocks [0,768): ka_weff_blob — Weff + direct MFMA-A-fragment blob write.
// Blocks [768,1024): kc_small — layer-0 blob + effective biases.
// whblob per (tl): [nf(8)][ks(16)][part(2)][lane(64)*8 halves]
// w0blob per t: [nf(8)][part(2)][512 halves]
// beff: [t][k(4)][256] fp32, k=0: b0+hb0, k>=1: bh[k-1]+hb[k]
// ---------------------------------------------------------------------------
__global__ __launch_bounds__(256) void kab(
    const float* __restrict__ latents, const float* __restrict__ W0,
    const float* __restrict__ b0, const float* __restrict__ bh,
    const float* __restrict__ HW0, const float* __restrict__ HB,
    const float* __restrict__ Wh, const float* __restrict__ HWh,
    _Float16* __restrict__ w0blob, float* __restrict__ beff,
    _Float16* __restrict__ whblob) {
  __shared__ float lat_t[8192];  // [k][f] : 256 x 32
  int tid = threadIdx.x, bid = blockIdx.x;

  if (bid >= 768) {
    // ---------------- kc_small ----------------
    int id = (bid - 768) * 256 + tid;
    if (id < 32768) {
      int t = id >> 10, rem = id & 1023;
      int r2 = rem & 127, part = r2 >> 6, lane = r2 & 63;
      int nf = rem >> 7;
      int o = nf * 32 + (lane & 31), kc = lane >> 5;
      const float* lat = latents + t * 256;
      H8 outv;
#pragma unroll
      for (int j = 0; j < 8; ++j) outv.h[j] = (_Float16)0.0f;
#pragma unroll
      for (int j = 0; j < 8; ++j) {
        int i = kc * 8 + j;
        if (i < 3) {
          const float* row = HW0 + (o * 3 + i) * 256;
          float s = W0[o * 3 + i];
          for (int k = 0; k < 256; k += 4)
            s += row[k] * lat[k] + row[k + 1] * lat[k + 1] +
                 row[k + 2] * lat[k + 2] + row[k + 3] * lat[k + 3];
          _Float16 hi = (_Float16)s;
          outv.h[j] = part ? (_Float16)((s - (float)hi) * LO_SCALE) : hi;
        }
      }
      *(f16x8*)(w0blob + (size_t)id * 8) = outv.v;
    } else {
      int v = id - 32768;
      int t = v >> 10, k = (v >> 8) & 3, hm = v & 255;
      float base = (k == 0) ? b0[hm] : bh[(k - 1) * 256 + hm];
      const float* lat = latents + t * 256;
      const float* row = HB + (size_t)(k * 256 + hm) * 256;
      float s = base;
      for (int kk = 0; kk < 256; kk += 4)
        s += row[kk] * lat[kk] + row[kk + 1] * lat[kk + 1] +
             row[kk + 2] * lat[kk + 2] + row[kk + 3] * lat[kk + 3];
      beff[v] = s;
    }
    return;
  }

  // ---------------- ka_weff_blob ----------------
  int h = bid & 1, ks = (bid >> 1) & 15, nf = (bid >> 5) & 7, l = bid >> 8;

  {
    int f = tid >> 3, kb = (tid & 7) * 32;
#pragma unroll
    for (int m = 0; m < 32; m += 4) {
      float4 v = *(const float4*)(latents + f * 256 + kb + m);
      lat_t[(kb + m + 0) * 32 + f] = v.x;
      lat_t[(kb + m + 1) * 32 + f] = v.y;
      lat_t[(kb + m + 2) * 32 + f] = v.z;
      lat_t[(kb + m + 3) * 32 + f] = v.w;
    }
  }
  __syncthreads();

  int oo = tid >> 3, jj = tid & 7;
  int o = nf * 32 + oo;
  int i = ks * 16 + h * 8 + jj;
  int r = o * 256 + i;
  const float* rowp = HWh + ((size_t)l * 65536 + (size_t)r) * 256;

  float acc[32];
#pragma unroll
  for (int f = 0; f < 32; ++f) acc[f] = 0.f;

  float curf[16], nxtf[16];
#pragma unroll
  for (int q = 0; q < 4; ++q)
    *(float4*)(curf + q * 4) = *(const float4*)(rowp + q * 4);

  for (int kc = 0; kc < 16; ++kc) {
    if (kc < 15) {
#pragma unroll
      for (int q = 0; q < 4; ++q)
        *(float4*)(nxtf + q * 4) = *(const float4*)(rowp + (kc + 1) * 16 + q * 4);
    }
    const float* lp = lat_t + kc * 512;
#pragma unroll
    for (int m = 0; m < 16; ++m) {
      float hw = curf[m];
#pragma unroll
      for (int fq = 0; fq < 8; ++fq) {
        float4 lv = *(const float4*)(lp + m * 32 + fq * 4);
        acc[fq * 4 + 0] += hw * lv.x;
        acc[fq * 4 + 1] += hw * lv.y;
        acc[fq * 4 + 2] += hw * lv.z;
        acc[fq * 4 + 3] += hw * lv.w;
      }
    }
#pragma unroll
    for (int q = 0; q < 16; ++q) curf[q] = nxtf[q];
  }

  float whv = Wh[l * 65536 + r];
  size_t cbase = (size_t)(nf * 16 + ks) * 1024 + (size_t)h * 256 + (size_t)tid;
#pragma unroll
  for (int t = 0; t < 32; ++t) {
    float w = acc[t] + whv;
    _Float16 hi = (_Float16)w;
    _Float16 lo = (_Float16)((w - (float)hi) * LO_SCALE);
    size_t b = (size_t)(t * 3 + l) * 131072 + cbase;
    whblob[b] = hi;
    whblob[b + 512] = lo;
  }
}

// ---------------------------------------------------------------------------
// Kernel B: fused SIREN. Block = one frame x 128 pixels, 8 waves (512 thr),
// each wave owns a 32-wide o-slice and ALL 4 pixel-fragments (pf) -> A-frag
// reused 4x (12 MFMA per 2KB A-load: ~43 B/cyc/CU L1 demand, under ceiling).
// Transposed GEMM D[o][px] = sum_k Weff[o][k]*x[px][k], mfma_f32_32x32x16_f16
// split-fp16 (hh->accA; hl+lh (lo pre-scaled 2048)->accB; out=accA+accB/2048).
// x in LDS hi/lo fp16. 141KB LDS -> 1 block/CU; cross-layer A-prefetch hides
// L2 latency under the epilogue VALU.
// ---------------------------------------------------------------------------
__global__ __launch_bounds__(512, 2) void kb_siren(
    const float* __restrict__ coords, const _Float16* __restrict__ whblob,
    const _Float16* __restrict__ w0blob, const float* __restrict__ beff,
    const float* __restrict__ Wf, const float* __restrict__ bf,
    float* __restrict__ out) {
  __shared__ _Float16 xs_hi[128 * 264];
  __shared__ _Float16 xs_lo[128 * 264];
  __shared__ float wf_s[768];
  __shared__ float red[1536];  // [kq(4)][px(128)][3]
  int tid = threadIdx.x;
  int bid0 = blockIdx.x;
  int bid = (bid0 & 7) * 128 + (bid0 >> 3);  // XCD swizzle: 4 frames per XCD
  int t = bid >> 5, tile = bid & 31;
  int wv = tid >> 6, lane = tid & 63, col = lane & 31, h = lane >> 5;

  if (tid < 192) *(float4*)(wf_s + tid * 4) = *(const float4*)(Wf + tid * 4);
  if (tid < 128) {
    const float* cp = coords + (size_t)(t * 4096 + tile * 128 + tid) * 3;
    float c0 = cp[0], c1 = cp[1], c2 = cp[2];
    H8 hv, lv, z;
#pragma unroll
    for (int j = 0; j < 8; ++j) { hv.h[j] = (_Float16)0.f; lv.h[j] = (_Float16)0.f; z.h[j] = (_Float16)0.f; }
    _Float16 h0 = (_Float16)c0, h1 = (_Float16)c1, h2 = (_Float16)c2;
    hv.h[0] = h0; hv.h[1] = h1; hv.h[2] = h2;
    lv.h[0] = (_Float16)((c0 - (float)h0) * LO_SCALE);
    lv.h[1] = (_Float16)((c1 - (float)h1) * LO_SCALE);
    lv.h[2] = (_Float16)((c2 - (float)h2) * LO_SCALE);
    *(f16x8*)(xs_hi + tid * 264) = hv.v;
    *(f16x8*)(xs_lo + tid * 264) = lv.v;
    *(f16x8*)(xs_hi + tid * 264 + 8) = z.v;
    *(f16x8*)(xs_lo + tid * 264 + 8) = z.v;
  }
  __syncthreads();

  f32x16 accA[4], accB[4];  // [pf]

  auto init_bias = [&](int bk) {
    const float* bp = beff + ((t * 4 + bk) << 8) + wv * 32 + h * 4;
#pragma unroll
    for (int rq = 0; rq < 4; ++rq) {
      float4 bvv = *(const float4*)(bp + rq * 8);
      float ba[4];
      *(float4*)ba = bvv;
#pragma unroll
      for (int q = 0; q < 4; ++q) {
#pragma unroll
        for (int pf = 0; pf < 4; ++pf) {
          accA[pf][rq * 4 + q] = ba[q];
          accB[pf][rq * 4 + q] = 0.f;
        }
      }
    }
  };

  auto aptr = [&](const _Float16* blobL, int NS, int ks) {
    return blobL + (size_t)((wv * NS + ks) * 2) * 512 + lane * 8;
  };

  // 12 MFMA per ks: per pf, load b (hi/lo) then 3 MFMAs; A reused 4x.
  auto mfma_ks = [&](f16x8 a0, f16x8 a1, int ks) {
#pragma unroll
    for (int pf = 0; pf < 4; ++pf) {
      int off = (pf * 32 + col) * 264 + ks * 16 + h * 8;
      f16x8 bh_ = *(const f16x8*)(xs_hi + off);
      f16x8 bl_ = *(const f16x8*)(xs_lo + off);
      accA[pf] = __builtin_amdgcn_mfma_f32_32x32x16_f16(a0, bh_, accA[pf], 0, 0, 0);
      accB[pf] = __builtin_amdgcn_mfma_f32_32x32x16_f16(a0, bl_, accB[pf], 0, 0, 0);
      accB[pf] = __builtin_amdgcn_mfma_f32_32x32x16_f16(a1, bh_, accB[pf], 0, 0, 0);
    }
  };

  // sine + split + in-register transpose (C rows=o -> B-frag k-contig) + store
  auto epilogue = [&]() {
#pragma unroll
    for (int pf = 0; pf < 4; ++pf)
#pragma unroll
      for (int r = 0; r < 16; ++r)
        accA[pf][r] = __sinf(30.0f * (accA[pf][r] + accB[pf][r] * LO_INV));
    __syncthreads();  // all waves done reading xs for this layer
#pragma unroll
    for (int pf = 0; pf < 4; ++pf)
#pragma unroll
      for (int g = 0; g < 2; ++g) {
        float seq[8];
#pragma unroll
        for (int q = 0; q < 4; ++q) {
          float oa = accA[pf][8 * g + q];       // row g*16 + q + 4h
          float ob = accA[pf][8 * g + 4 + q];   // row g*16 + 8 + q + 4h
          float send = h ? oa : ob;
          float recv = __shfl_xor(send, 32, 64);
          seq[q]     = h ? recv : oa;
          seq[4 + q] = h ? ob : recv;
        }
        H8 hv, lv;
#pragma unroll
        for (int j = 0; j < 8; ++j) {
          _Float16 hi = (_Float16)seq[j];
          hv.h[j] = hi;
          lv.h[j] = (_Float16)((seq[j] - (float)hi) * LO_SCALE);
        }
        int off = (pf * 32 + col) * 264 + wv * 32 + g * 16 + h * 8;
        *(f16x8*)(xs_hi + off) = hv.v;
        *(f16x8*)(xs_lo + off) = lv.v;
      }
    __syncthreads();
  };

  const _Float16* bl0 = whblob + (size_t)(t * 3) * 131072;

  // ---- layer 0 (K=16 zero-padded; coords staged in xs[.., 0..15])
  init_bias(0);
  {
    const _Float16* p = aptr(w0blob + (size_t)t * 8192, 1, 0);
    f16x8 a0 = *(const f16x8*)p, a1 = *(const f16x8*)(p + 512);
    mfma_ks(a0, a1, 0);
  }
  // prefetch hidden layer 0, ks 0 before the epilogue (hide L2 latency)
  f16x8 c0, c1;
  {
    const _Float16* p = aptr(bl0, 16, 0);
    c0 = *(const f16x8*)p;
    c1 = *(const f16x8*)(p + 512);
  }
  epilogue();

  // ---- hidden layers
#pragma unroll
  for (int li = 0; li < 3; ++li) {
    init_bias(li + 1);
    const _Float16* bl = whblob + (size_t)(t * 3 + li) * 131072;
    const _Float16* bln = whblob + (size_t)(t * 3 + li + 1) * 131072;
#pragma unroll
    for (int ks = 0; ks < 16; ++ks) {
      f16x8 n0, n1;
      bool have_next = (ks < 15) || (li < 2);
      if (ks < 15) {
        const _Float16* p = aptr(bl, 16, ks + 1);
        n0 = *(const f16x8*)p;
        n1 = *(const f16x8*)(p + 512);
      } else if (li < 2) {
        const _Float16* p = aptr(bln, 16, 0);
        n0 = *(const f16x8*)p;
        n1 = *(const f16x8*)(p + 512);
      }
      mfma_ks(c0, c1, ks);
      if (have_next) { c0 = n0; c1 = n1; }
    }
    epilogue();
  }

  // ---- final linear (3 outputs), VALU from LDS; 4 k-groups of 64
  {
    float pc0 = 0.f, pc1 = 0.f, pc2 = 0.f;
    int px = tid & 127, kq = tid >> 7;
#pragma unroll
    for (int cc = 0; cc < 8; ++cc) {
      int k0 = kq * 64 + cc * 8;
      H8 hv, lv;
      hv.v = *(const f16x8*)(xs_hi + px * 264 + k0);
      lv.v = *(const f16x8*)(xs_lo + px * 264 + k0);
#pragma unroll
      for (int j = 0; j < 8; ++j) {
        float xv = (float)hv.h[j] + (float)lv.h[j] * LO_INV;
        pc0 += xv * wf_s[k0 + j];
        pc1 += xv * wf_s[256 + k0 + j];
        pc2 += xv * wf_s[512 + k0 + j];
      }
    }
    red[kq * 384 + px * 3 + 0] = pc0;
    red[kq * 384 + px * 3 + 1] = pc1;
    red[kq * 384 + px * 3 + 2] = pc2;
    __syncthreads();
    if (tid < 384) {
      int p2 = tid / 3, c = tid - p2 * 3;
      float s = bf[c];
#pragma unroll
      for (int q = 0; q < 4; ++q) s += red[q * 384 + p2 * 3 + c];
      out[(size_t)(t * 4096 + tile * 128 + p2) * 3 + c] = s;
    }
  }
}

// ---------------------------------------------------------------------------
extern "C" void kernel_launch(void* const* d_in, const int* in_sizes, int n_in,
                              void* d_out, int out_size, void* d_ws, size_t ws_size,
                              hipStream_t stream) {
  const float* coords  = (const float*)d_in[0];
  const float* latents = (const float*)d_in[1];
  const float* W0      = (const float*)d_in[2];
  const float* b0      = (const float*)d_in[3];
  const float* Wh      = (const float*)d_in[4];
  const float* bh      = (const float*)d_in[5];
  const float* Wf      = (const float*)d_in[6];
  const float* bf      = (const float*)d_in[7];
  const float* HW0     = (const float*)d_in[8];
  const float* HWh     = (const float*)d_in[9];
  const float* HB      = (const float*)d_in[10];
  float* outp = (float*)d_out;

  char* w = (char*)d_ws;
  _Float16* whblob = (_Float16*)w;                   // 12,582,912 halves
  _Float16* w0blob = (_Float16*)(w + 25165824);      // 262,144 halves
  float*    beff   = (float*)(w + 25690112);         // 32,768 floats

  kab<<<1024, 256, 0, stream>>>(latents, W0, b0, bh, HW0, HB, Wh, HWh,
                                w0blob, beff, whblob);
  kb_siren<<<1024, 512, 0, stream>>>(coords, whblob, w0blob, beff, Wf, bf, outp);
}